// Round 5
// baseline (18.077 us; speedup 1.0000x reference)
//
#include <hip/hip_runtime.h>

#define TIMESTEPS 1000
#define BATCH 64
#define HH 256
#define WW 256
#define WAVES_PER_BLOCK 4
#define NBLOCKS 1280                               // 5 blocks/CU x 256 CUs
#define NWAVES (NBLOCKS * WAVES_PER_BLOCK)         // 5120 waves, 3.2 rows each
#define HBINS 1024                                 // bins padded 1000 -> 1024

// Wave-private histograms + generation tags, no __syncthreads. 20 waves/CU
// (5 x 32KB blocks = 160KB LDS exactly) to fill DS-pipe issue bubbles --
// round-4 showed global-load latency is already hidden, so concurrency for
// the LDS pipe is the remaining lever. Wave W handles rows
// [W*16/5, (W+1)*16/5)  (3 or 4 rows; 5120*3.2 = 16384).
__global__ __launch_bounds__(256) void holo_mse_kernel(
    const float* __restrict__ rec, const float* __restrict__ tgt,
    unsigned int* __restrict__ partials)
{
    __shared__ unsigned int hist[WAVES_PER_BLOCK][2][HBINS];  // 32 KB/block

    const int tid  = threadIdx.x;
    const int wave = tid >> 6;
    const int lane = tid & 63;

    unsigned int* hr = &hist[wave][0][0];
    unsigned int* ht = &hist[wave][1][0];

    // one-time init (gen 0 == invalid); contiguous b128 writes, uniform banks
    const uint4 z4 = make_uint4(0u, 0u, 0u, 0u);
    #pragma unroll
    for (int k = 0; k < 4; ++k) {
        *(uint4*)&hr[k * 256 + lane * 4] = z4;
        *(uint4*)&ht[k * 256 + lane * 4] = z4;
    }
    __builtin_amdgcn_wave_barrier();

    const int W  = blockIdx.x * WAVES_PER_BLOCK + wave;   // 0..5119
    const int r0 = (W * 16) / 5;                          // W*16 <= 81904, fits
    const int r1 = ((W + 1) * 16) / 5;

    unsigned int acc = 0;

    for (int row = r0; row < r1; ++row) {
        const unsigned int genHi = (unsigned int)(row - r0 + 1) << 8;  // 1..4

        const float4 vr4 = *(const float4*)&rec[(size_t)row * WW + lane * 4];
        const float4 vt4 = *(const float4*)&tgt[(size_t)row * WW + lane * 4];
        const float vr[4] = {vr4.x, vr4.y, vr4.z, vr4.w};
        const float vt[4] = {vt4.x, vt4.y, vt4.z, vt4.w};

        #pragma unroll
        for (int j = 0; j < 4; ++j) {
            const unsigned int y = (unsigned int)(lane * 4 + j);
            if (vr[j] != 0.0f) {
                int t = (int)(vr[j] * 1000.0f) - 1;   // trunc == astype(int32)
                if (t < 0) t += TIMESTEPS;            // python wrap: -1 -> 999
                if ((unsigned)t < TIMESTEPS) atomicMax(&hr[t], genHi | y);
            }
            if (vt[j] != 0.0f) {
                int t = (int)(vt[j] * 1000.0f) - 1;
                if (t < 0) t += TIMESTEPS;
                if ((unsigned)t < TIMESTEPS) atomicMax(&ht[t], genHi | y);
            }
        }
        __builtin_amdgcn_wave_barrier();   // reads stay after this row's atomics
        // (DS ops within a wave complete in order; barrier is compiler-only)

        // accumulate: contiguous b128 reads (k*256 + lane*4 -> all 32 banks)
        #pragma unroll
        for (int k = 0; k < 4; ++k) {
            const uint4 a = *(const uint4*)&hr[k * 256 + lane * 4];
            const uint4 b = *(const uint4*)&ht[k * 256 + lane * 4];
            const unsigned int ar[4] = {a.x, a.y, a.z, a.w};
            const unsigned int br[4] = {b.x, b.y, b.z, b.w};
            #pragma unroll
            for (int j = 0; j < 4; ++j) {
                unsigned int ur = ar[j] - genHi;
                unsigned int yr = (ur < 256u) ? ur : 0u;
                unsigned int ut = br[j] - genHi;
                unsigned int yt = (ut < 256u) ? ut : 0u;
                int d = (int)yr - (int)yt;
                acc += (unsigned int)(d * d);   // per-lane <= ~4.2M, exact
            }
        }
        __builtin_amdgcn_wave_barrier();   // next row's atomics stay below reads
    }

    // wave-64 shuffle reduce; one partial per wave, zero contention, no
    // __syncthreads anywhere in this kernel.
    #pragma unroll
    for (int off = 32; off > 0; off >>= 1) acc += __shfl_down(acc, off, 64);
    if (lane == 0) partials[W] = acc;
}

// Single block sums 5120 u32 partials exactly in u64 (20 KB, vectorized).
__global__ __launch_bounds__(256) void reduce_kernel(
    const unsigned int* __restrict__ partials, float* __restrict__ out)
{
    const int tid = threadIdx.x;
    const uint4* p4 = (const uint4*)partials;      // 1280 uint4 = 5 * 256
    unsigned long long s = 0;
    #pragma unroll
    for (int k = 0; k < 5; ++k) {
        const uint4 p = p4[k * 256 + tid];
        s += (unsigned long long)p.x + p.y + p.z + p.w;
    }

    #pragma unroll
    for (int off = 32; off > 0; off >>= 1) s += __shfl_down(s, off, 64);

    __shared__ unsigned long long wsum[4];
    const int wave = tid >> 6;
    if ((tid & 63) == 0) wsum[wave] = s;
    __syncthreads();

    if (tid == 0) {
        unsigned long long tot = wsum[0] + wsum[1] + wsum[2] + wsum[3];
        const double denom = (double)BATCH * (double)HH * (double)TIMESTEPS; // 16,384,000
        out[0] = (float)((double)tot / denom);
    }
}

extern "C" void kernel_launch(void* const* d_in, const int* in_sizes, int n_in,
                              void* d_out, int out_size, void* d_ws, size_t ws_size,
                              hipStream_t stream) {
    const float* rec = (const float*)d_in[0];
    const float* tgt = (const float*)d_in[1];
    float* out = (float*)d_out;
    unsigned int* partials = (unsigned int*)d_ws;   // 5120 * 4 B = 20 KB scratch

    holo_mse_kernel<<<NBLOCKS, 256, 0, stream>>>(rec, tgt, partials);
    reduce_kernel<<<1, 256, 0, stream>>>(partials, out);
}